// Round 12
// baseline (155.201 us; speedup 1.0000x reference)
//
#include <hip/hip_runtime.h>
#include <hip/hip_bf16.h>

#define N_NODES 50000
#define N_EDGES 600000
#define HID 128
#define SCAN_BLOCKS ((N_NODES + 255) / 256)   // 196

typedef __attribute__((ext_vector_type(8))) __bf16 bf16x8;
typedef __attribute__((ext_vector_type(4))) float f32x4;

static __device__ __forceinline__ unsigned short f2b(float v) {
    return __builtin_bit_cast(unsigned short, (__bf16)v);
}

// ---------------- fused prep: cast x->bf16, build V1/V2, zero fill + cursor ----------------

#define NCAST (N_NODES * HID / 8)          // 800000 threads, 8 elems each
#define NVT   (2 * 128 * 256 / 8)          // 8192 threads
#define NFILL (N_NODES / 4)                // 12500 threads, int4 each
#define NPREP (NCAST + NVT + NFILL)

__global__ __launch_bounds__(256) void k_prep(const float* __restrict__ x,
                                              const float* __restrict__ W1l, const float* __restrict__ W1r,
                                              const float* __restrict__ W2l, const float* __restrict__ W2r,
                                              unsigned short* __restrict__ xb,
                                              unsigned short* __restrict__ V1,
                                              unsigned short* __restrict__ V2,
                                              int* __restrict__ fill,
                                              int* __restrict__ cursor) {
    int idx = blockIdx.x * 256 + threadIdx.x;
    if (idx < NCAST) {
        const float4* xp = (const float4*)(x + (size_t)idx * 8);
        float4 a = xp[0], b = xp[1];
        uint4 o;
        o.x = f2b(a.x) | ((unsigned)f2b(a.y) << 16);
        o.y = f2b(a.z) | ((unsigned)f2b(a.w) << 16);
        o.z = f2b(b.x) | ((unsigned)f2b(b.y) << 16);
        o.w = f2b(b.z) | ((unsigned)f2b(b.w) << 16);
        *(uint4*)(xb + (size_t)idx * 8) = o;
    } else if (idx < NCAST + NVT) {
        int t = idx - NCAST;
        int i0 = t * 8;                 // flat elem index into [V1;V2]
        int which = i0 >> 15;           // 0 -> V1, 1 -> V2
        const float* Wl = which ? W2l : W1l;
        const float* Wr = which ? W2r : W1r;
        unsigned short* V = which ? V2 : V1;
        int ii = i0 & 32767;
        int j = ii >> 8, k0 = ii & 255; // k0 multiple of 8: all 8 elems same side
        const float* Wp = (k0 < HID) ? (Wl + j * HID + k0) : (Wr + j * HID + (k0 - HID));
        const float4* wp4 = (const float4*)Wp;
        float4 a = wp4[0], b = wp4[1];
        uint4 o;
        o.x = f2b(a.x) | ((unsigned)f2b(a.y) << 16);
        o.y = f2b(a.z) | ((unsigned)f2b(a.w) << 16);
        o.z = f2b(b.x) | ((unsigned)f2b(b.y) << 16);
        o.w = f2b(b.z) | ((unsigned)f2b(b.w) << 16);
        *(uint4*)(V + ii) = o;
    } else if (idx < NPREP) {
        int z = idx - (NCAST + NVT);
        *(int4*)(fill + z * 4) = make_int4(0, 0, 0, 0);
    } else if (idx == NPREP) {
        *cursor = 0;
    }
}

// ---------------- CSR build ----------------

__global__ void k_deg(const int* __restrict__ dst, int* __restrict__ fill, int ne) {
    int e = blockIdx.x * blockDim.x + threadIdx.x;
    if (e < ne) atomicAdd(&fill[dst[e]], 1);
}

// single-pass offsets: intra-block scan + atomic cursor for block base.
__global__ __launch_bounds__(256) void k_offsets(int* __restrict__ fill,
                                                 int* __restrict__ row_start,
                                                 int* __restrict__ dg,
                                                 float* __restrict__ inv_deg,
                                                 int* __restrict__ cursor, int n) {
    __shared__ int s[256];
    __shared__ int base;
    int tid = threadIdx.x;
    int i = blockIdx.x * 256 + tid;
    int c = (i < n) ? fill[i] : 0;
    s[tid] = c;
    __syncthreads();
#pragma unroll
    for (int off = 1; off < 256; off <<= 1) {
        int t = (tid >= off) ? s[tid - off] : 0;
        __syncthreads();
        s[tid] += t;
        __syncthreads();
    }
    if (tid == 255) base = atomicAdd(cursor, s[255]);
    __syncthreads();
    if (i < n) {
        row_start[i] = base + s[tid] - c;
        dg[i] = c;
        inv_deg[i] = 1.0f / (float)max(c, 1);
        fill[i] = 0;   // reset for placement pass
    }
}

__global__ void k_place(const int* __restrict__ src, const int* __restrict__ dst,
                        const int* __restrict__ row_start, int* __restrict__ fill,
                        int* __restrict__ csr, int ne) {
    int e = blockIdx.x * blockDim.x + threadIdx.x;
    if (e < ne) {
        int d = dst[e];
        int pos = atomicAdd(&fill[d], 1);
        csr[row_start[d] + pos] = src[e];
    }
}

// ---------------- mean aggregation (two 16-lane halves per node, uint4 loads) ----------------

static __device__ __forceinline__ void acc_bf8(uint4 v, float* a) {
    a[0] += __uint_as_float(v.x << 16);
    a[1] += __uint_as_float(v.x & 0xffff0000u);
    a[2] += __uint_as_float(v.y << 16);
    a[3] += __uint_as_float(v.y & 0xffff0000u);
    a[4] += __uint_as_float(v.z << 16);
    a[5] += __uint_as_float(v.z & 0xffff0000u);
    a[6] += __uint_as_float(v.w << 16);
    a[7] += __uint_as_float(v.w & 0xffff0000u);
}

__global__ __launch_bounds__(256) void k_agg(const unsigned short* __restrict__ xb,
                                             const int* __restrict__ csr,
                                             const int* __restrict__ row_start,
                                             const int* __restrict__ dg,
                                             const float* __restrict__ inv_deg,
                                             unsigned short* __restrict__ aggB, int n) {
    int g = (blockIdx.x * blockDim.x + threadIdx.x) >> 5;
    int lane = threadIdx.x & 31;
    if (g >= n) return;
    int e0 = row_start[g];
    int e1 = e0 + dg[g];
    int half = lane >> 4;     // 0: even-offset edges, 1: odd-offset edges
    int c16 = lane & 15;      // which 16B chunk of the 256B row
    float a[8] = {0.f, 0.f, 0.f, 0.f, 0.f, 0.f, 0.f, 0.f};

    int e = e0 + half;        // this half's edge stream, stride 2
    for (; e + 6 < e1; e += 8) {
        int s0 = csr[e + 0], s1 = csr[e + 2], s2 = csr[e + 4], s3 = csr[e + 6];
        uint4 v0 = *(const uint4*)(xb + (size_t)s0 * HID + c16 * 8);
        uint4 v1 = *(const uint4*)(xb + (size_t)s1 * HID + c16 * 8);
        uint4 v2 = *(const uint4*)(xb + (size_t)s2 * HID + c16 * 8);
        uint4 v3 = *(const uint4*)(xb + (size_t)s3 * HID + c16 * 8);
        acc_bf8(v0, a); acc_bf8(v1, a); acc_bf8(v2, a); acc_bf8(v3, a);
    }
    for (; e + 2 < e1; e += 4) {
        int s0 = csr[e + 0], s1 = csr[e + 2];
        uint4 v0 = *(const uint4*)(xb + (size_t)s0 * HID + c16 * 8);
        uint4 v1 = *(const uint4*)(xb + (size_t)s1 * HID + c16 * 8);
        acc_bf8(v0, a); acc_bf8(v1, a);
    }
    if (e < e1) {
        int s0 = csr[e];
        uint4 v0 = *(const uint4*)(xb + (size_t)s0 * HID + c16 * 8);
        acc_bf8(v0, a);
    }

#pragma unroll
    for (int j = 0; j < 8; ++j) a[j] += __shfl_xor(a[j], 16);

    if (half == 0) {
        float inv = inv_deg[g];
        uint4 o;
        o.x = f2b(a[0] * inv) | ((unsigned)f2b(a[1] * inv) << 16);
        o.y = f2b(a[2] * inv) | ((unsigned)f2b(a[3] * inv) << 16);
        o.z = f2b(a[4] * inv) | ((unsigned)f2b(a[5] * inv) << 16);
        o.w = f2b(a[6] * inv) | ((unsigned)f2b(a[7] * inv) << 16);
        *(uint4*)(aggB + (size_t)g * HID + c16 * 8) = o;
    }
}

// ---------------- MFMA GEMM: out = [agg | xin] @ V_T^T + bias ----------------
// 512 threads (8 waves), BM=128, K=256. SINGLE-STAGE: all of VT (64KB, both
// k-halves) goes into swizzled LDS once; all 8 A-fragments (both phases) are
// issued as direct global loads before the ONE barrier; then all 64 MFMAs run
// with no further barriers.

__global__ __launch_bounds__(512) void k_gemm(const unsigned short* __restrict__ aggB,
                                              const unsigned short* __restrict__ xinB,
                                              const unsigned short* __restrict__ VT,
                                              const float* __restrict__ bias,
                                              float* __restrict__ outF,
                                              unsigned short* __restrict__ outB,
                                              int mode /*1 = relu+bf16 out, 0 = fp32 out*/,
                                              int nrows) {
    __shared__ char Bs[65536];
    int tid = threadIdx.x;
    int w = tid >> 6, l = tid & 63;
    int r0 = blockIdx.x * 128;

    f32x4 acc[8] = {};
    int kgrp = (l >> 4) * 8;

    int arow_g = r0 + w * 16 + (l & 15);
    int arow_c = (arow_g < nrows) ? arow_g : 0;   // clamp; results discarded in epilogue

    // ---- stage ALL of VT: 2 phases x 128 rows x 128 elems (4096 x 16B) ----
#pragma unroll
    for (int q = 0; q < 8; ++q) {
        int c = tid + q * 512;
        int p = c >> 11;          // which k-half
        int cc = c & 2047;
        int j = cc >> 4, c16 = cc & 15;
        uint4 v = *(const uint4*)(VT + (size_t)j * 256 + p * 128 + c16 * 8);
        int byt = p * 32768 + ((j * 256 + c16 * 16) ^ ((j & 7) << 4));
        *(uint4*)(Bs + byt) = v;
    }

    // ---- all 8 A fragments (both phases) direct from global, issued pre-barrier ----
    bf16x8 afr[2][4];
#pragma unroll
    for (int s = 0; s < 4; ++s) {
        afr[0][s] = *(const bf16x8*)(aggB + (size_t)arow_c * HID + s * 32 + kgrp);
        afr[1][s] = *(const bf16x8*)(xinB + (size_t)arow_c * HID + s * 32 + kgrp);
    }

    __syncthreads();

    // ---- all MFMAs, no further barriers ----
#pragma unroll
    for (int p = 0; p < 2; ++p) {
#pragma unroll
        for (int s = 0; s < 4; ++s) {
            int koff = (s * 32 + kgrp) * 2;
#pragma unroll
            for (int cc = 0; cc < 8; ++cc) {
                int brow = cc * 16 + (l & 15);
                bf16x8 b = *(const bf16x8*)(Bs + p * 32768 + ((brow * 256 + koff) ^ ((brow & 7) << 4)));
                acc[cc] = __builtin_amdgcn_mfma_f32_16x16x32_bf16(afr[p][s], b, acc[cc], 0, 0, 0);
            }
        }
    }

    // ---- epilogue: D[row=(l>>4)*4+i][col=cc*16+(l&15)] per wave tile ----
    int lo = l & 15, hi = l >> 4;
#pragma unroll
    for (int cc = 0; cc < 8; ++cc) {
        int col = cc * 16 + lo;
        float bv = bias[col];
#pragma unroll
        for (int i = 0; i < 4; ++i) {
            int gr = r0 + w * 16 + hi * 4 + i;
            if (gr < nrows) {
                float v = acc[cc][i] + bv;
                if (mode) {
                    v = fmaxf(v, 0.f);
                    outB[(size_t)gr * HID + col] = f2b(v);
                } else {
                    outF[(size_t)gr * HID + col] = v;
                }
            }
        }
    }
}

// ---------------- launch ----------------

extern "C" void kernel_launch(void* const* d_in, const int* in_sizes, int n_in,
                              void* d_out, int out_size, void* d_ws, size_t ws_size,
                              hipStream_t stream) {
    const float* x   = (const float*)d_in[0];
    const int*   ei  = (const int*)d_in[1];
    const float* W1l = (const float*)d_in[2];
    const float* b1l = (const float*)d_in[3];
    const float* W1r = (const float*)d_in[4];
    const float* W2l = (const float*)d_in[5];
    const float* b2l = (const float*)d_in[6];
    const float* W2r = (const float*)d_in[7];
    float* out = (float*)d_out;

    const int* src = ei;
    const int* dst = ei + N_EDGES;

    char* w = (char*)d_ws;
    unsigned short* aggB = (unsigned short*)(w);                    // 12,800,000 B
    unsigned short* buf0 = (unsigned short*)(w + 12800000);         // 12,800,000 B (xb, then hb in place)
    int*   csr     = (int*)(w + 25600000);                          //  2,400,000 B
    int*   row_off = (int*)(w + 28000000);                          //    200,192 B
    int*   fill    = (int*)(w + 28200192);                          //    200,192 B
    float* inv_deg = (float*)(w + 28400384);                        //    200,192 B
    int*   dg      = (int*)(w + 28600576);                          //    200,192 B
    unsigned short* V1 = (unsigned short*)(w + 28800768);           //     65,536 B
    unsigned short* V2 = (unsigned short*)(w + 28866304);           //     65,536 B
    int*   cursor  = (int*)(w + 28931840);                          //        256 B

    // 1) fused prep: cast x -> bf16 (buf0), build V1/V2, zero fill + cursor
    k_prep<<<(NPREP + 1 + 255) / 256, 256, 0, stream>>>(x, W1l, W1r, W2l, W2r, buf0, V1, V2, fill, cursor);

    // 2) degree histogram
    k_deg<<<(N_EDGES + 255) / 256, 256, 0, stream>>>(dst, fill, N_EDGES);

    // 3) single-pass offsets (atomic block base; unordered disjoint ranges)
    k_offsets<<<SCAN_BLOCKS, 256, 0, stream>>>(fill, row_off, dg, inv_deg, cursor, N_NODES);

    // 4) place edges into CSR buckets
    k_place<<<(N_EDGES + 255) / 256, 256, 0, stream>>>(src, dst, row_off, fill, csr, N_EDGES);

    const int gemm_grid = (N_NODES + 127) / 128;  // 391

    // layer 1: agg1 <- mean(xb); h(bf16, relu) -> buf0 in place
    k_agg<<<(N_NODES * 32 + 255) / 256, 256, 0, stream>>>(buf0, csr, row_off, dg, inv_deg, aggB, N_NODES);
    k_gemm<<<gemm_grid, 512, 0, stream>>>(aggB, buf0, V1, b1l, out, buf0, 1, N_NODES);

    // layer 2: agg2 <- mean(hb); out(fp32) -> d_out
    k_agg<<<(N_NODES * 32 + 255) / 256, 256, 0, stream>>>(buf0, csr, row_off, dg, inv_deg, aggB, N_NODES);
    k_gemm<<<gemm_grid, 512, 0, stream>>>(aggB, buf0, V2, b2l, out, buf0, 0, N_NODES);
}

// Round 13
// 148.318 us; speedup vs baseline: 1.0464x; 1.0464x over previous
//
#include <hip/hip_runtime.h>
#include <hip/hip_bf16.h>

#define N_NODES 50000
#define N_EDGES 600000
#define HID 128
#define SCAN_BLOCKS ((N_NODES + 255) / 256)   // 196

typedef __attribute__((ext_vector_type(8))) __bf16 bf16x8;
typedef __attribute__((ext_vector_type(4))) float f32x4;

static __device__ __forceinline__ unsigned short f2b(float v) {
    return __builtin_bit_cast(unsigned short, (__bf16)v);
}

// ---------------- fused prep: cast x->bf16, build V1/V2, zero fill + cursor ----------------

#define NCAST (N_NODES * HID / 8)          // 800000 threads, 8 elems each
#define NVT   (2 * 128 * 256 / 8)          // 8192 threads
#define NFILL (N_NODES / 4)                // 12500 threads, int4 each
#define NPREP (NCAST + NVT + NFILL)

__global__ __launch_bounds__(256) void k_prep(const float* __restrict__ x,
                                              const float* __restrict__ W1l, const float* __restrict__ W1r,
                                              const float* __restrict__ W2l, const float* __restrict__ W2r,
                                              unsigned short* __restrict__ xb,
                                              unsigned short* __restrict__ V1,
                                              unsigned short* __restrict__ V2,
                                              int* __restrict__ fill,
                                              int* __restrict__ cursor) {
    int idx = blockIdx.x * 256 + threadIdx.x;
    if (idx < NCAST) {
        const float4* xp = (const float4*)(x + (size_t)idx * 8);
        float4 a = xp[0], b = xp[1];
        uint4 o;
        o.x = f2b(a.x) | ((unsigned)f2b(a.y) << 16);
        o.y = f2b(a.z) | ((unsigned)f2b(a.w) << 16);
        o.z = f2b(b.x) | ((unsigned)f2b(b.y) << 16);
        o.w = f2b(b.z) | ((unsigned)f2b(b.w) << 16);
        *(uint4*)(xb + (size_t)idx * 8) = o;
    } else if (idx < NCAST + NVT) {
        int t = idx - NCAST;
        int i0 = t * 8;                 // flat elem index into [V1;V2]
        int which = i0 >> 15;           // 0 -> V1, 1 -> V2
        const float* Wl = which ? W2l : W1l;
        const float* Wr = which ? W2r : W1r;
        unsigned short* V = which ? V2 : V1;
        int ii = i0 & 32767;
        int j = ii >> 8, k0 = ii & 255; // k0 multiple of 8: all 8 elems same side
        const float* Wp = (k0 < HID) ? (Wl + j * HID + k0) : (Wr + j * HID + (k0 - HID));
        const float4* wp4 = (const float4*)Wp;
        float4 a = wp4[0], b = wp4[1];
        uint4 o;
        o.x = f2b(a.x) | ((unsigned)f2b(a.y) << 16);
        o.y = f2b(a.z) | ((unsigned)f2b(a.w) << 16);
        o.z = f2b(b.x) | ((unsigned)f2b(b.y) << 16);
        o.w = f2b(b.z) | ((unsigned)f2b(b.w) << 16);
        *(uint4*)(V + ii) = o;
    } else if (idx < NPREP) {
        int z = idx - (NCAST + NVT);
        *(int4*)(fill + z * 4) = make_int4(0, 0, 0, 0);
    } else if (idx == NPREP) {
        *cursor = 0;
    }
}

// ---------------- CSR build ----------------

__global__ void k_deg(const int* __restrict__ dst, int* __restrict__ fill, int ne) {
    int e = blockIdx.x * blockDim.x + threadIdx.x;
    if (e < ne) atomicAdd(&fill[dst[e]], 1);
}

// single-pass offsets: intra-block scan + atomic cursor for block base.
__global__ __launch_bounds__(256) void k_offsets(int* __restrict__ fill,
                                                 int* __restrict__ row_start,
                                                 int* __restrict__ dg,
                                                 float* __restrict__ inv_deg,
                                                 int* __restrict__ cursor, int n) {
    __shared__ int s[256];
    __shared__ int base;
    int tid = threadIdx.x;
    int i = blockIdx.x * 256 + tid;
    int c = (i < n) ? fill[i] : 0;
    s[tid] = c;
    __syncthreads();
#pragma unroll
    for (int off = 1; off < 256; off <<= 1) {
        int t = (tid >= off) ? s[tid - off] : 0;
        __syncthreads();
        s[tid] += t;
        __syncthreads();
    }
    if (tid == 255) base = atomicAdd(cursor, s[255]);
    __syncthreads();
    if (i < n) {
        row_start[i] = base + s[tid] - c;
        dg[i] = c;
        inv_deg[i] = 1.0f / (float)max(c, 1);
        fill[i] = 0;   // reset for placement pass
    }
}

__global__ void k_place(const int* __restrict__ src, const int* __restrict__ dst,
                        const int* __restrict__ row_start, int* __restrict__ fill,
                        int* __restrict__ csr, int ne) {
    int e = blockIdx.x * blockDim.x + threadIdx.x;
    if (e < ne) {
        int d = dst[e];
        int pos = atomicAdd(&fill[d], 1);
        csr[row_start[d] + pos] = src[e];
    }
}

// ---------------- mean aggregation (two 16-lane halves per node, uint4 loads) ----------------

static __device__ __forceinline__ void acc_bf8(uint4 v, float* a) {
    a[0] += __uint_as_float(v.x << 16);
    a[1] += __uint_as_float(v.x & 0xffff0000u);
    a[2] += __uint_as_float(v.y << 16);
    a[3] += __uint_as_float(v.y & 0xffff0000u);
    a[4] += __uint_as_float(v.z << 16);
    a[5] += __uint_as_float(v.z & 0xffff0000u);
    a[6] += __uint_as_float(v.w << 16);
    a[7] += __uint_as_float(v.w & 0xffff0000u);
}

__global__ __launch_bounds__(256) void k_agg(const unsigned short* __restrict__ xb,
                                             const int* __restrict__ csr,
                                             const int* __restrict__ row_start,
                                             const int* __restrict__ dg,
                                             const float* __restrict__ inv_deg,
                                             unsigned short* __restrict__ aggB, int n) {
    int g = (blockIdx.x * blockDim.x + threadIdx.x) >> 5;
    int lane = threadIdx.x & 31;
    if (g >= n) return;
    int e0 = row_start[g];
    int e1 = e0 + dg[g];
    int half = lane >> 4;     // 0: even-offset edges, 1: odd-offset edges
    int c16 = lane & 15;      // which 16B chunk of the 256B row
    float a[8] = {0.f, 0.f, 0.f, 0.f, 0.f, 0.f, 0.f, 0.f};

    int e = e0 + half;        // this half's edge stream, stride 2
    for (; e + 6 < e1; e += 8) {
        int s0 = csr[e + 0], s1 = csr[e + 2], s2 = csr[e + 4], s3 = csr[e + 6];
        uint4 v0 = *(const uint4*)(xb + (size_t)s0 * HID + c16 * 8);
        uint4 v1 = *(const uint4*)(xb + (size_t)s1 * HID + c16 * 8);
        uint4 v2 = *(const uint4*)(xb + (size_t)s2 * HID + c16 * 8);
        uint4 v3 = *(const uint4*)(xb + (size_t)s3 * HID + c16 * 8);
        acc_bf8(v0, a); acc_bf8(v1, a); acc_bf8(v2, a); acc_bf8(v3, a);
    }
    for (; e + 2 < e1; e += 4) {
        int s0 = csr[e + 0], s1 = csr[e + 2];
        uint4 v0 = *(const uint4*)(xb + (size_t)s0 * HID + c16 * 8);
        uint4 v1 = *(const uint4*)(xb + (size_t)s1 * HID + c16 * 8);
        acc_bf8(v0, a); acc_bf8(v1, a);
    }
    if (e < e1) {
        int s0 = csr[e];
        uint4 v0 = *(const uint4*)(xb + (size_t)s0 * HID + c16 * 8);
        acc_bf8(v0, a);
    }

#pragma unroll
    for (int j = 0; j < 8; ++j) a[j] += __shfl_xor(a[j], 16);

    if (half == 0) {
        float inv = inv_deg[g];
        uint4 o;
        o.x = f2b(a[0] * inv) | ((unsigned)f2b(a[1] * inv) << 16);
        o.y = f2b(a[2] * inv) | ((unsigned)f2b(a[3] * inv) << 16);
        o.z = f2b(a[4] * inv) | ((unsigned)f2b(a[5] * inv) << 16);
        o.w = f2b(a[6] * inv) | ((unsigned)f2b(a[7] * inv) << 16);
        *(uint4*)(aggB + (size_t)g * HID + c16 * 8) = o;
    }
}

// ---------------- MFMA GEMM: out = [agg | xin] @ V_T^T + bias ----------------
// 512 threads (8 waves), BM=128, K=256 in 2 phases of 128.
// A is NOT LDS-staged: each wave owns 16 rows with zero cross-wave reuse, so
// lanes load their A fragments (16B) directly from global (L2-hot).
// Only B (VT, shared by all waves) is staged in swizzled LDS (32KB).

__global__ __launch_bounds__(512) void k_gemm(const unsigned short* __restrict__ aggB,
                                              const unsigned short* __restrict__ xinB,
                                              const unsigned short* __restrict__ VT,
                                              const float* __restrict__ bias,
                                              float* __restrict__ outF,
                                              unsigned short* __restrict__ outB,
                                              int mode /*1 = relu+bf16 out, 0 = fp32 out*/,
                                              int nrows) {
    __shared__ char Bs[32768];
    int tid = threadIdx.x;
    int w = tid >> 6, l = tid & 63;
    int r0 = blockIdx.x * 128;

    f32x4 acc[8] = {};
    int kgrp = (l >> 4) * 8;

    int arow_g = r0 + w * 16 + (l & 15);
    int arow_c = (arow_g < nrows) ? arow_g : 0;   // clamp; results discarded in epilogue

    for (int p = 0; p < 2; ++p) {
        const unsigned short* Asrc = p ? xinB : aggB;

        // stage Bs: VT rows j, k-half p (128x128 bf16, swizzled)
#pragma unroll
        for (int q = 0; q < 4; ++q) {
            int c = tid + q * 512;
            int j = c >> 4, c16 = c & 15;
            uint4 v = *(const uint4*)(VT + (size_t)j * 256 + p * 128 + c16 * 8);
            int byt = (j * 256 + c16 * 16) ^ ((j & 7) << 4);
            *(uint4*)(Bs + byt) = v;
        }

        // A fragments direct from global (issue before barrier; latency hides under it)
        bf16x8 afr[4];
#pragma unroll
        for (int s = 0; s < 4; ++s)
            afr[s] = *(const bf16x8*)(Asrc + (size_t)arow_c * HID + s * 32 + kgrp);

        __syncthreads();

#pragma unroll
        for (int s = 0; s < 4; ++s) {
            int koff = (s * 32 + kgrp) * 2;
#pragma unroll
            for (int cc = 0; cc < 8; ++cc) {
                int brow = cc * 16 + (l & 15);
                bf16x8 b = *(const bf16x8*)(Bs + ((brow * 256 + koff) ^ ((brow & 7) << 4)));
                acc[cc] = __builtin_amdgcn_mfma_f32_16x16x32_bf16(afr[s], b, acc[cc], 0, 0, 0);
            }
        }
        __syncthreads();
    }

    // epilogue: D[row=(l>>4)*4+i][col=cc*16+(l&15)] per wave tile
    int lo = l & 15, hi = l >> 4;
#pragma unroll
    for (int cc = 0; cc < 8; ++cc) {
        int col = cc * 16 + lo;
        float bv = bias[col];
#pragma unroll
        for (int i = 0; i < 4; ++i) {
            int gr = r0 + w * 16 + hi * 4 + i;
            if (gr < nrows) {
                float v = acc[cc][i] + bv;
                if (mode) {
                    v = fmaxf(v, 0.f);
                    outB[(size_t)gr * HID + col] = f2b(v);
                } else {
                    outF[(size_t)gr * HID + col] = v;
                }
            }
        }
    }
}

// ---------------- launch ----------------

extern "C" void kernel_launch(void* const* d_in, const int* in_sizes, int n_in,
                              void* d_out, int out_size, void* d_ws, size_t ws_size,
                              hipStream_t stream) {
    const float* x   = (const float*)d_in[0];
    const int*   ei  = (const int*)d_in[1];
    const float* W1l = (const float*)d_in[2];
    const float* b1l = (const float*)d_in[3];
    const float* W1r = (const float*)d_in[4];
    const float* W2l = (const float*)d_in[5];
    const float* b2l = (const float*)d_in[6];
    const float* W2r = (const float*)d_in[7];
    float* out = (float*)d_out;

    const int* src = ei;
    const int* dst = ei + N_EDGES;

    char* w = (char*)d_ws;
    unsigned short* aggB = (unsigned short*)(w);                    // 12,800,000 B
    unsigned short* buf0 = (unsigned short*)(w + 12800000);         // 12,800,000 B (xb, then hb in place)
    int*   csr     = (int*)(w + 25600000);                          //  2,400,000 B
    int*   row_off = (int*)(w + 28000000);                          //    200,192 B
    int*   fill    = (int*)(w + 28200192);                          //    200,192 B
    float* inv_deg = (float*)(w + 28400384);                        //    200,192 B
    int*   dg      = (int*)(w + 28600576);                          //    200,192 B
    unsigned short* V1 = (unsigned short*)(w + 28800768);           //     65,536 B
    unsigned short* V2 = (unsigned short*)(w + 28866304);           //     65,536 B
    int*   cursor  = (int*)(w + 28931840);                          //        256 B

    // 1) fused prep: cast x -> bf16 (buf0), build V1/V2, zero fill + cursor
    k_prep<<<(NPREP + 1 + 255) / 256, 256, 0, stream>>>(x, W1l, W1r, W2l, W2r, buf0, V1, V2, fill, cursor);

    // 2) degree histogram
    k_deg<<<(N_EDGES + 255) / 256, 256, 0, stream>>>(dst, fill, N_EDGES);

    // 3) single-pass offsets (atomic block base; unordered disjoint ranges)
    k_offsets<<<SCAN_BLOCKS, 256, 0, stream>>>(fill, row_off, dg, inv_deg, cursor, N_NODES);

    // 4) place edges into CSR buckets
    k_place<<<(N_EDGES + 255) / 256, 256, 0, stream>>>(src, dst, row_off, fill, csr, N_EDGES);

    const int gemm_grid = (N_NODES + 127) / 128;  // 391

    // layer 1: agg1 <- mean(xb); h(bf16, relu) -> buf0 in place
    k_agg<<<(N_NODES * 32 + 255) / 256, 256, 0, stream>>>(buf0, csr, row_off, dg, inv_deg, aggB, N_NODES);
    k_gemm<<<gemm_grid, 512, 0, stream>>>(aggB, buf0, V1, b1l, out, buf0, 1, N_NODES);

    // layer 2: agg2 <- mean(hb); out(fp32) -> d_out
    k_agg<<<(N_NODES * 32 + 255) / 256, 256, 0, stream>>>(buf0, csr, row_off, dg, inv_deg, aggB, N_NODES);
    k_gemm<<<gemm_grid, 512, 0, stream>>>(aggB, buf0, V2, b2l, out, buf0, 0, N_NODES);
}